// Round 5
// baseline (1207.209 us; speedup 1.0000x reference)
//
#include <hip/hip_runtime.h>
#include <cstdint>

typedef _Float16 f16x2 __attribute__((ext_vector_type(2)));

// Fast activations: ~2-ulp exp/div is plenty vs the 1e-3 absmax threshold.
__device__ __forceinline__ float fsig(float x) {
  x = fminf(fmaxf(x, -30.f), 30.f);
  return __fdividef(1.f, 1.f + __expf(-x));
}
__device__ __forceinline__ float ftanh_(float x) {
  x = fminf(fmaxf(x, -15.f), 15.f);
  float e = __expf(2.f * x);
  return __fdividef(e - 1.f, e + 1.f);
}

// ---------------------------------------------------------------------------
// Layer 1: 262144 independent LSTM chains, seq=16, input=1, hidden=8.
// TWO chains per thread, t-loop ROLLED (R2's 16x-unrolled 2-chain body was
// ~13K instr -> I$ thrash; R3's rolled 1-chain was s_load-latency bound at
// 153 us). Each uniform weight load (scalar pipe) now feeds 2 chains' FMAs.
// ---------------------------------------------------------------------------
__global__ __launch_bounds__(256) void lstm1_kernel(
    const float* __restrict__ x, const float* __restrict__ Wih,
    const float* __restrict__ Whh, const float* __restrict__ bih,
    const float* __restrict__ bhh, float* __restrict__ h1) {
  const int tid = threadIdx.x;
  const int n0 = blockIdx.x * 512 + tid;  // chain ids
  const int n1 = n0 + 256;
  const float* __restrict__ xp0 = x + (size_t)n0 * 16;
  const float* __restrict__ xp1 = x + (size_t)n1 * 16;

  float h0[8], c0[8], h1a[8], c1a[8];
#pragma unroll
  for (int k = 0; k < 8; ++k) { h0[k] = c0[k] = h1a[k] = c1a[k] = 0.f; }

  for (int t = 0; t < 16; ++t) {  // rolled: keep body I$-resident
    float xv0 = xp0[t];
    float xv1 = xp1[t];
    float hn0[8], hn1[8];
#pragma unroll
    for (int k = 0; k < 8; ++k) {
      float acc0[4], acc1[4];
#pragma unroll
      for (int gi = 0; gi < 4; ++gi) {
        const int r = gi * 8 + k;
        float bb = bih[r] + bhh[r];
        float wx = Wih[r];
        float a0 = fmaf(wx, xv0, bb);
        float a1 = fmaf(wx, xv1, bb);
#pragma unroll
        for (int j = 0; j < 8; ++j) {
          float w = Whh[r * 8 + j];  // uniform -> s_load, feeds both chains
          a0 = fmaf(w, h0[j], a0);
          a1 = fmaf(w, h1a[j], a1);
        }
        acc0[gi] = a0; acc1[gi] = a1;
      }
      {
        float iv = fsig(acc0[0]), fv = fsig(acc0[1]);
        float gv = ftanh_(acc0[2]), ov = fsig(acc0[3]);
        c0[k] = fmaf(fv, c0[k], iv * gv);
        hn0[k] = ov * ftanh_(c0[k]);
      }
      {
        float iv = fsig(acc1[0]), fv = fsig(acc1[1]);
        float gv = ftanh_(acc1[2]), ov = fsig(acc1[3]);
        c1a[k] = fmaf(fv, c1a[k], iv * gv);
        hn1[k] = ov * ftanh_(c1a[k]);
      }
    }
#pragma unroll
    for (int k = 0; k < 8; ++k) { h0[k] = hn0[k]; h1a[k] = hn1[k]; }
  }
  float4* op0 = (float4*)(h1 + (size_t)n0 * 8);
  op0[0] = make_float4(h0[0], h0[1], h0[2], h0[3]);
  op0[1] = make_float4(h0[4], h0[5], h0[6], h0[7]);
  float4* op1 = (float4*)(h1 + (size_t)n1 * 8);
  op1[0] = make_float4(h1a[0], h1a[1], h1a[2], h1a[3]);
  op1[1] = make_float4(h1a[4], h1a[5], h1a[6], h1a[7]);
}

// ---------------------------------------------------------------------------
// Layer 2: B=256 recurrences -> 1 block (512 thr, 8 waves) per CU.
// Identical to R4 EXCEPT __launch_bounds__(512, 2): R4's (512,4) capped the
// allocator at 128 VGPRs/wave, evicting the 64 asm-pinned half2 weights
// (VGPR_Count=64 proved it). Occupancy is grid-limited to 2 waves/SIMD
// anyway (256 blocks = 1 block/CU), so a 256-VGPR budget costs nothing.
// ---------------------------------------------------------------------------
__global__ __launch_bounds__(512, 2) void lstm2_kernel(
    const float* __restrict__ h1, const float* __restrict__ Wih,
    const float* __restrict__ Whh, const float* __restrict__ bih,
    const float* __restrict__ bhh, const float* __restrict__ W1,
    const float* __restrict__ b1, const float* __restrict__ W2,
    const float* __restrict__ b2, float* __restrict__ out) {
  __shared__ float sG[2][4][128];  // [buf][gate i,f,g,o][hidden k]
  const int b = blockIdx.x;
  const int t = threadIdx.x;
  const int lane = t & 63;
  const int gate = t >> 7;  // 0:i 1:f 2:g 3:o — wave-uniform

  // --- W_hh row t as 64 packed half2, asm-pinned into VGPRs ---
  int w2[64];
  {
    const float2* Wr = (const float2*)(Whh + (size_t)t * 128);
#pragma unroll
    for (int i = 0; i < 64; ++i) {
      float2 v = Wr[i];
      f16x2 p;
      p.x = (_Float16)v.x;
      p.y = (_Float16)v.y;
      w2[i] = __builtin_bit_cast(int, p);
    }
  }
#pragma unroll
  for (int i = 0; i < 64; i += 8)
    asm volatile("" : "+v"(w2[i]), "+v"(w2[i + 1]), "+v"(w2[i + 2]),
                      "+v"(w2[i + 3]), "+v"(w2[i + 4]), "+v"(w2[i + 5]),
                      "+v"(w2[i + 6]), "+v"(w2[i + 7]));

  float wi[8];
  {
    const float4* I = (const float4*)(Wih + (size_t)t * 8);
    float4 a = I[0], bb = I[1];
    wi[0] = a.x; wi[1] = a.y; wi[2] = a.z; wi[3] = a.w;
    wi[4] = bb.x; wi[5] = bb.y; wi[6] = bb.z; wi[7] = bb.w;
  }
  asm volatile("" : "+v"(wi[0]), "+v"(wi[1]), "+v"(wi[2]), "+v"(wi[3]),
                    "+v"(wi[4]), "+v"(wi[5]), "+v"(wi[6]), "+v"(wi[7]));
  const float bias = bih[t] + bhh[t];
  const float* __restrict__ xbase = h1 + (size_t)b * 8192;  // [1024][8]

  // replicated per-wave state: lane holds h[2*lane], h[2*lane+1] (f16 packed)
  f16x2 h2; h2.x = (_Float16)0.f; h2.y = (_Float16)0.f;
  float cx = 0.f, cy = 0.f;

  float xs[8];
#pragma unroll
  for (int j = 0; j < 8; ++j) xs[j] = xbase[j];  // uniform -> s_load

  for (int ts = 0; ts < 1024; ++ts) {
    // prefetch next step's x (uniform scalar loads)
    const float* xn_p = xbase + ((ts + 1) & 1023) * 8;
    float xn[8];
#pragma unroll
    for (int j = 0; j < 8; ++j) xn[j] = xn_p[j];

    float a0 = bias, a1 = 0.f, a2 = 0.f, a3 = 0.f;
#pragma unroll
    for (int j = 0; j < 8; ++j) a0 = fmaf(wi[j], xs[j], a0);

    const int h2i = __builtin_bit_cast(int, h2);
#pragma unroll
    for (int l = 0; l < 64; l += 4) {  // readlane bcast + dot2, 4-way ILP
      a0 = __builtin_amdgcn_fdot2(
          __builtin_bit_cast(f16x2, w2[l]),
          __builtin_bit_cast(f16x2, __builtin_amdgcn_readlane(h2i, l)), a0, false);
      a1 = __builtin_amdgcn_fdot2(
          __builtin_bit_cast(f16x2, w2[l + 1]),
          __builtin_bit_cast(f16x2, __builtin_amdgcn_readlane(h2i, l + 1)), a1, false);
      a2 = __builtin_amdgcn_fdot2(
          __builtin_bit_cast(f16x2, w2[l + 2]),
          __builtin_bit_cast(f16x2, __builtin_amdgcn_readlane(h2i, l + 2)), a2, false);
      a3 = __builtin_amdgcn_fdot2(
          __builtin_bit_cast(f16x2, w2[l + 3]),
          __builtin_bit_cast(f16x2, __builtin_amdgcn_readlane(h2i, l + 3)), a3, false);
    }
    float acc = (a0 + a1) + (a2 + a3);
    float act = (gate == 2) ? ftanh_(acc) : fsig(acc);
    const int buf = ts & 1;
    sG[buf][gate][t & 127] = act;
    __syncthreads();  // the only barrier per step (sG double-buffered)
    {
      float2 iv = *(const float2*)&sG[buf][0][2 * lane];
      float2 fv = *(const float2*)&sG[buf][1][2 * lane];
      float2 gv = *(const float2*)&sG[buf][2][2 * lane];
      float2 ov = *(const float2*)&sG[buf][3][2 * lane];
      cx = fmaf(fv.x, cx, iv.x * gv.x);
      cy = fmaf(fv.y, cy, iv.y * gv.y);
      h2.x = (_Float16)(ov.x * ftanh_(cx));
      h2.y = (_Float16)(ov.y * ftanh_(cy));
    }
#pragma unroll
    for (int j = 0; j < 8; ++j) xs[j] = xn[j];
  }

  // Epilogue: out[b] = (h @ W1.T + b1) @ W2.T + b2, wave 0 (has full h).
  if (t < 64) {
    const float2* w1r = (const float2*)(W1 + (size_t)t * 128);
    float a = b1[t];
    const int h2i = __builtin_bit_cast(int, h2);
#pragma unroll
    for (int l = 0; l < 64; ++l) {
      float2 wv = w1r[l];
      f16x2 ww;
      ww.x = (_Float16)wv.x;
      ww.y = (_Float16)wv.y;
      a = __builtin_amdgcn_fdot2(
          ww, __builtin_bit_cast(f16x2, __builtin_amdgcn_readlane(h2i, l)), a, false);
    }
    float v = a * W2[t];
#pragma unroll
    for (int off = 32; off > 0; off >>= 1) v += __shfl_down(v, off);
    if (t == 0) out[b] = v + b2[0];
  }
}

extern "C" void kernel_launch(void* const* d_in, const int* in_sizes, int n_in,
                              void* d_out, int out_size, void* d_ws, size_t ws_size,
                              hipStream_t stream) {
  const float* x    = (const float*)d_in[0];
  // d_in[1] is the unused python scalar `data`
  const float* Wih1 = (const float*)d_in[2];
  const float* Whh1 = (const float*)d_in[3];
  const float* bih1 = (const float*)d_in[4];
  const float* bhh1 = (const float*)d_in[5];
  const float* Wih2 = (const float*)d_in[6];
  const float* Whh2 = (const float*)d_in[7];
  const float* bih2 = (const float*)d_in[8];
  const float* bhh2 = (const float*)d_in[9];
  const float* W1   = (const float*)d_in[10];
  const float* b1   = (const float*)d_in[11];
  const float* W2   = (const float*)d_in[12];
  const float* b2   = (const float*)d_in[13];
  float* out = (float*)d_out;

  float* h1 = (float*)d_ws;  // 256*1024*8 fp32 = 8 MB scratch

  lstm1_kernel<<<512, 256, 0, stream>>>(x, Wih1, Whh1, bih1, bhh1, h1);
  lstm2_kernel<<<256, 512, 0, stream>>>(h1, Wih2, Whh2, bih2, bhh2,
                                        W1, b1, W2, b2, out);
}

// Round 6
// 932.351 us; speedup vs baseline: 1.2948x; 1.2948x over previous
//
#include <hip/hip_runtime.h>
#include <cstdint>

typedef _Float16 f16x2 __attribute__((ext_vector_type(2)));

// Fast activations: ~2-ulp exp/div is plenty vs the 1e-3 absmax threshold.
__device__ __forceinline__ float fsig(float x) {
  x = fminf(fmaxf(x, -30.f), 30.f);
  return __fdividef(1.f, 1.f + __expf(-x));
}
__device__ __forceinline__ float ftanh_(float x) {
  x = fminf(fmaxf(x, -15.f), 15.f);
  float e = __expf(2.f * x);
  return __fdividef(e - 1.f, e + 1.f);
}
__device__ __forceinline__ int packf16(float a, float b) {
  f16x2 p; p.x = (_Float16)a; p.y = (_Float16)b;
  return __builtin_bit_cast(int, p);
}
__device__ __forceinline__ float dot2(int w, int h, float acc) {
  return __builtin_amdgcn_fdot2(__builtin_bit_cast(f16x2, w),
                                __builtin_bit_cast(f16x2, h), acc, false);
}

// ---------------------------------------------------------------------------
// Layer 1: 262144 independent LSTM chains, seq=16, input=1, hidden=8.
// One chain per thread. Weights f16-packed into ~160 asm-pinned VGPRs
// (dot2 on the h-part). t-loop rolled (I$), x prefetched one step ahead.
// ---------------------------------------------------------------------------
__global__ __launch_bounds__(256, 2) void lstm1_kernel(
    const float* __restrict__ x, const float* __restrict__ Wih,
    const float* __restrict__ Whh, const float* __restrict__ bih,
    const float* __restrict__ bhh, float* __restrict__ h1) {
  const int n = blockIdx.x * 256 + threadIdx.x;  // chain id = b*S + s

  // whh2[r*4+j] = (Whh[r][2j], Whh[r][2j+1]) as f16 pair
  int whh2[128];
#pragma unroll
  for (int r = 0; r < 32; ++r) {
#pragma unroll
    for (int j = 0; j < 4; ++j) {
      float2 v = ((const float2*)(Whh + r * 8))[j];
      whh2[r * 4 + j] = packf16(v.x, v.y);
    }
  }
  // wxb[r] = (Wih[r], bih[r]+bhh[r]) as f16 pair; dotted with (x_t, 1)
  int wxb[32];
#pragma unroll
  for (int r = 0; r < 32; ++r) wxb[r] = packf16(Wih[r], bih[r] + bhh[r]);

#pragma unroll
  for (int i = 0; i < 128; i += 8)
    asm volatile("" : "+v"(whh2[i]), "+v"(whh2[i + 1]), "+v"(whh2[i + 2]),
                      "+v"(whh2[i + 3]), "+v"(whh2[i + 4]), "+v"(whh2[i + 5]),
                      "+v"(whh2[i + 6]), "+v"(whh2[i + 7]));
#pragma unroll
  for (int i = 0; i < 32; i += 8)
    asm volatile("" : "+v"(wxb[i]), "+v"(wxb[i + 1]), "+v"(wxb[i + 2]),
                      "+v"(wxb[i + 3]), "+v"(wxb[i + 4]), "+v"(wxb[i + 5]),
                      "+v"(wxb[i + 6]), "+v"(wxb[i + 7]));

  const float* __restrict__ xp = x + (size_t)n * 16;
  float c[8];
  int h2[4];  // h as 4 packed f16 pairs
#pragma unroll
  for (int k = 0; k < 8; ++k) c[k] = 0.f;
#pragma unroll
  for (int j = 0; j < 4; ++j) h2[j] = 0;

  float xv = xp[0];
  for (int t = 0; t < 16; ++t) {  // rolled: keep body I$-resident
    float xn = xp[(t + 1) & 15];  // prefetch (wraps harmlessly at t=15)
    const int xt1 = packf16(xv, 1.f);
    float hn[8];
#pragma unroll
    for (int k = 0; k < 8; ++k) {
      float acc[4];
#pragma unroll
      for (int gi = 0; gi < 4; ++gi) {
        const int r = gi * 8 + k;
        float a = dot2(wxb[r], xt1, 0.f);
        a = dot2(whh2[r * 4 + 0], h2[0], a);
        a = dot2(whh2[r * 4 + 1], h2[1], a);
        a = dot2(whh2[r * 4 + 2], h2[2], a);
        a = dot2(whh2[r * 4 + 3], h2[3], a);
        acc[gi] = a;
      }
      float iv = fsig(acc[0]), fv = fsig(acc[1]);
      float gv = ftanh_(acc[2]), ov = fsig(acc[3]);
      c[k] = fmaf(fv, c[k], iv * gv);
      hn[k] = ov * ftanh_(c[k]);
    }
#pragma unroll
    for (int j = 0; j < 4; ++j) h2[j] = packf16(hn[2 * j], hn[2 * j + 1]);
    xv = xn;
  }
  // unpack final h for fp32 output
  float ho[8];
#pragma unroll
  for (int j = 0; j < 4; ++j) {
    f16x2 p = __builtin_bit_cast(f16x2, h2[j]);
    ho[2 * j] = (float)p.x;
    ho[2 * j + 1] = (float)p.y;
  }
  float4* op = (float4*)(h1 + (size_t)n * 8);
  op[0] = make_float4(ho[0], ho[1], ho[2], ho[3]);
  op[1] = make_float4(ho[4], ho[5], ho[6], ho[7]);
}

// ---------------------------------------------------------------------------
// Layer 2: B=256 recurrences -> 1 block (512 thr, 8 waves) per CU.
// Thread t owns gate row t (64 pinned half2 weight VGPRs, as R4/R5) BUT the
// h broadcast is restructured: every thread keeps the FULL h vector as 64
// half2 VGPRs, refreshed each step by 16 same-address ds_read_b128 broadcasts
// (free of conflicts). Inner loop = 64 pure VGPRxVGPR v_dot2 — no readlane,
// no SGPR operands, no VALU->SGPR hazards (R5's 435 instr/wave-step vs ~165
// model pointed at the readlane path). Two barriers/step: gates -> (c,h)
// update by owner threads -> republished h.
// ---------------------------------------------------------------------------
__global__ __launch_bounds__(512, 2) void lstm2_kernel(
    const float* __restrict__ h1, const float* __restrict__ Wih,
    const float* __restrict__ Whh, const float* __restrict__ bih,
    const float* __restrict__ bhh, const float* __restrict__ W1,
    const float* __restrict__ b1, const float* __restrict__ W2,
    const float* __restrict__ b2, float* __restrict__ out) {
  __shared__ float sG[128 * 5];            // [k][gate], pad 5 -> 2-way max
  __shared__ __align__(16) int sH2i[64];   // h as 64 half2 (256 B)
  const int b = blockIdx.x;
  const int t = threadIdx.x;
  const int gate = t >> 7;   // 0:i 1:f 2:g 3:o — wave-uniform
  const int k = t & 127;     // hidden index of this row

  // --- W_hh row t as 64 packed half2, asm-pinned ---
  int w2[64];
  {
    const float2* Wr = (const float2*)(Whh + (size_t)t * 128);
#pragma unroll
    for (int i = 0; i < 64; ++i) {
      float2 v = Wr[i];
      w2[i] = packf16(v.x, v.y);
    }
  }
#pragma unroll
  for (int i = 0; i < 64; i += 8)
    asm volatile("" : "+v"(w2[i]), "+v"(w2[i + 1]), "+v"(w2[i + 2]),
                      "+v"(w2[i + 3]), "+v"(w2[i + 4]), "+v"(w2[i + 5]),
                      "+v"(w2[i + 6]), "+v"(w2[i + 7]));

  float wi[8];
  {
    const float4* I = (const float4*)(Wih + (size_t)t * 8);
    float4 a = I[0], bb = I[1];
    wi[0] = a.x; wi[1] = a.y; wi[2] = a.z; wi[3] = a.w;
    wi[4] = bb.x; wi[5] = bb.y; wi[6] = bb.z; wi[7] = bb.w;
  }
  const float bias = bih[t] + bhh[t];
  const float* __restrict__ xbase = h1 + (size_t)b * 8192;  // [1024][8]

  // full h replica in registers (64 half2), and owner-side cell state
  int h2f[64];
#pragma unroll
  for (int i = 0; i < 64; ++i) h2f[i] = 0;
  float c = 0.f;  // valid for t < 128 (owner of hidden index k)

  float xs[8];
#pragma unroll
  for (int j = 0; j < 8; ++j) xs[j] = xbase[j];  // uniform -> s_load

  for (int ts = 0; ts < 1024; ++ts) {
    // prefetch next step's x (uniform scalar loads)
    const float* xn_p = xbase + ((ts + 1) & 1023) * 8;
    float xn[8];
#pragma unroll
    for (int j = 0; j < 8; ++j) xn[j] = xn_p[j];

    float a0 = bias, a1 = 0.f, a2 = 0.f, a3 = 0.f;
#pragma unroll
    for (int j = 0; j < 8; ++j) a0 = fmaf(wi[j], xs[j], a0);
#pragma unroll
    for (int l = 0; l < 64; l += 4) {  // pure VGPR dot2, 4-way ILP
      a0 = dot2(w2[l], h2f[l], a0);
      a1 = dot2(w2[l + 1], h2f[l + 1], a1);
      a2 = dot2(w2[l + 2], h2f[l + 2], a2);
      a3 = dot2(w2[l + 3], h2f[l + 3], a3);
    }
    float acc = (a0 + a1) + (a2 + a3);
    sG[k * 5 + gate] = (gate == 2) ? ftanh_(acc) : fsig(acc);
    __syncthreads();

    if (t < 128) {  // owner of hidden index k: update c, publish h[k] as f16
      float iv = sG[k * 5 + 0], fv = sG[k * 5 + 1];
      float gv = sG[k * 5 + 2], ov = sG[k * 5 + 3];
      c = fmaf(fv, c, iv * gv);
      ((_Float16*)sH2i)[k] = (_Float16)(ov * ftanh_(c));
    }
    __syncthreads();

    {  // refresh full-h replica: 16 broadcast ds_read_b128
      const int4* src = (const int4*)sH2i;
#pragma unroll
      for (int q = 0; q < 16; ++q) {
        int4 v = src[q];
        h2f[4 * q] = v.x; h2f[4 * q + 1] = v.y;
        h2f[4 * q + 2] = v.z; h2f[4 * q + 3] = v.w;
      }
    }
#pragma unroll
    for (int j = 0; j < 8; ++j) xs[j] = xn[j];
  }

  // Epilogue: out[b] = (h @ W1.T + b1) @ W2.T + b2 on wave 0 (h2f = h_T).
  if (t < 64) {
    const float2* w1r = (const float2*)(W1 + (size_t)t * 128);
    float a = b1[t];
#pragma unroll
    for (int l = 0; l < 64; ++l) {
      float2 wv = w1r[l];
      f16x2 p = __builtin_bit_cast(f16x2, h2f[l]);
      a = fmaf(wv.x, (float)p.x, a);
      a = fmaf(wv.y, (float)p.y, a);
    }
    float v = a * W2[t];
#pragma unroll
    for (int off = 32; off > 0; off >>= 1) v += __shfl_down(v, off);
    if (t == 0) out[b] = v + b2[0];
  }
}

extern "C" void kernel_launch(void* const* d_in, const int* in_sizes, int n_in,
                              void* d_out, int out_size, void* d_ws, size_t ws_size,
                              hipStream_t stream) {
  const float* x    = (const float*)d_in[0];
  // d_in[1] is the unused python scalar `data`
  const float* Wih1 = (const float*)d_in[2];
  const float* Whh1 = (const float*)d_in[3];
  const float* bih1 = (const float*)d_in[4];
  const float* bhh1 = (const float*)d_in[5];
  const float* Wih2 = (const float*)d_in[6];
  const float* Whh2 = (const float*)d_in[7];
  const float* bih2 = (const float*)d_in[8];
  const float* bhh2 = (const float*)d_in[9];
  const float* W1   = (const float*)d_in[10];
  const float* b1   = (const float*)d_in[11];
  const float* W2   = (const float*)d_in[12];
  const float* b2   = (const float*)d_in[13];
  float* out = (float*)d_out;

  float* h1 = (float*)d_ws;  // 256*1024*8 fp32 = 8 MB scratch

  lstm1_kernel<<<1024, 256, 0, stream>>>(x, Wih1, Whh1, bih1, bhh1, h1);
  lstm2_kernel<<<256, 512, 0, stream>>>(h1, Wih2, Whh2, bih2, bhh2,
                                        W1, b1, W2, b2, out);
}